// Round 5
// baseline (180.201 us; speedup 1.0000x reference)
//
#include <hip/hip_runtime.h>

// RegLoss: l1(masked preds, targets) + 0.1 * mse(masked edge directions)
// preds, targets: [128, 1024, 151] fp32. Output: 1 fp32 scalar.
//
// Identities:
//   targets * (targets != 0) == targets       (masking targets is identity)
//   (m*pd - m*td)^2 == m*(pd - td)^2          (m in {0,1})
//   diff/(len+tiny) == (d2 > 0 ? diff*rsq(d2) : 0)  (~1e-7 rel; thresh 2.4e-2)
//
// R11: UNSINKABLE prefetch via volatile inline-asm global_load_dwordx4.
// History: R6 (DMA d2/16w), R7 (DMA d1/32w), R9 (reg d?/16w), R10
// (reg + sched_barrier) are ALL 63.5us / 2.49 TB/s, and in ALL of them
// the emitted code had the same shape: burst 6 loads -> full-latency
// stall -> ~600cy compute with nothing in flight. R9/R10 proof: VGPR_Count
// pinned at 40 => the 24 staging regs were never live across the edge
// phase => the compiler sank the prefetch to its use. sched_barrier(0)
// failed because the sinking happens at IR level (plain loads may cross a
// no-memory intrinsic); rule #18: only volatile asm w/ memory clobber pins
// at both IR and MIR level.
//
// Mechanism: prefetch loads are asm volatile ("memory") -- cannot be
// deleted/moved across the ds_writes before them or the ds_reads after
// them => issued before the ~600cy edge gather, latency hides under it,
// and each wave keeps ~6KB in flight during compute (time-averaged
// ~96KB/CU at 16 waves) instead of 0. Consumption: manual
// s_waitcnt vmcnt(0) + sched_barrier(0) (rule #18: VALU consumers of asm
// results hoist past waitcnt w/o the fence) at next iteration top.
// WAR on reusing the staging regs is safe: in-order issue means the
// ds_write/acc_l1 consumers of chunk c issued before the chunk c+1 loads.
//
// Verifiable signature: VGPR_Count MUST rise (~64-96; volatile-asm defs
// live across compute_edges). WRITE_SIZE must stay ~130KB (no spill). If
// both hold and duration is still ~63.5us => burst-vs-overlap is proven
// irrelevant => 2.49 TB/s is this pattern's serving-rate roofline.

#define N_ROWS   (128 * 1024)
#define ROW      151
#define N_EDGES  47
#define GRID     2048
#define BLOCK    256
#define CHUNKS   4                     // 2048 blk * 4 waves * 4 chunks * 4 rows
#define CHUNK_ROWS 4
#define CHUNK_DW (CHUNK_ROWS * ROW)    // 604 dwords per array per chunk
#define CHUNK_TASKS (CHUNK_ROWS * N_EDGES) // 188
#define BUF_DW (2 * CHUNK_DW)          // [preds 604][targets 604] = 4832 B

#if __has_builtin(__builtin_amdgcn_rsqf)
__device__ __forceinline__ float fast_rsq(float x) { return __builtin_amdgcn_rsqf(x); }
#else
__device__ __forceinline__ float fast_rsq(float x) {
    float r; asm volatile("v_rsq_f32 %0, %1" : "=v"(r) : "v"(x)); return r;
}
#endif

template <int N>
__device__ __forceinline__ void wait_vm() {
    asm volatile("s_waitcnt vmcnt(%0)" :: "n"(N) : "memory");
}

// Volatile, memory-clobbering 16B global load: cannot be sunk or deleted.
// Result regs are NOT vmcnt-tracked by the compiler -- consumer side must
// execute wait_vm<0>() + sched_barrier(0) before reading the value.
__device__ __forceinline__ float4 ldg4_pin(const float* p) {
    float4 r;
    asm volatile("global_load_dwordx4 %0, %1, off"
                 : "=v"(r) : "v"(p) : "memory");
    return r;
}

__device__ __forceinline__ void st4(float* __restrict__ p, float4 v) {
    *reinterpret_cast<float4*>(p) = v;
}

// packed: low16 = parent*3 (dword offset in row), high16 = child*3
#define E(p, c) ((unsigned)((p) * 3) | ((unsigned)((c) * 3) << 16))
__constant__ unsigned c_edge[N_EDGES] = {
    E(0,1),  E(1,2),  E(2,3),  E(3,29), E(1,5),  E(5,6),  E(6,8),  E(8,9),
    E(8,13), E(8,17), E(8,21), E(8,25), E(9,10), E(10,11),E(11,12),E(13,14),
    E(14,15),E(15,16),E(17,18),E(18,19),E(19,20),E(21,22),E(22,23),E(23,24),
    E(25,26),E(26,27),E(27,28),E(29,30),E(29,34),E(29,38),E(29,42),E(29,46),
    E(30,31),E(31,32),E(32,33),E(34,35),E(35,36),E(36,37),E(38,39),E(39,40),
    E(40,41),E(42,43),E(43,44),E(44,45),E(46,47),E(47,48),E(48,49)};

// pre-summed LDS dword addresses: aP/aC = row_off + joint*3, aM = row_off + e
struct EdgeAddr { int aP[3], aC[3], aM[3]; };

__device__ __forceinline__ void acc_l1(float4 pv, float4 tv, float& l1) {
    float a0 = (tv.x != 0.f) ? pv.x : 0.f;
    float a1 = (tv.y != 0.f) ? pv.y : 0.f;
    float a2 = (tv.z != 0.f) ? pv.z : 0.f;
    float a3 = (tv.w != 0.f) ? pv.w : 0.f;
    l1 += fabsf(a0 - tv.x) + fabsf(a1 - tv.y)
        + fabsf(a2 - tv.z) + fabsf(a3 - tv.w);
}

// 188 edge tasks from LDS, mask applied at read time.
// k=0,1 fully active (tasks 0..127); k=2 active for lane<60 (tasks 128..187).
__device__ __forceinline__ void compute_edges(
        const float* __restrict__ B, const EdgeAddr& ea, int lane, float& vel) {
    const float* __restrict__ Bp = B;
    const float* __restrict__ Bt = B + CHUNK_DW;
#pragma unroll
    for (int k = 0; k < 3; ++k) {
        if (k < 2 || lane < (CHUNK_TASKS - 128)) {
            int aP = ea.aP[k], aC = ea.aC[k], aM = ea.aM[k];
            float tpx = Bt[aP], tpy = Bt[aP + 1], tpz = Bt[aP + 2];
            float tcx = Bt[aC], tcy = Bt[aC + 1], tcz = Bt[aC + 2];
            float ppx = Bp[aP], ppy = Bp[aP + 1], ppz = Bp[aP + 2];
            float pcx = Bp[aC], pcy = Bp[aC + 1], pcz = Bp[aC + 2];
            // masked preds
            float apx = (tpx != 0.f) ? ppx : 0.f;
            float apy = (tpy != 0.f) ? ppy : 0.f;
            float apz = (tpz != 0.f) ? ppz : 0.f;
            float acx = (tcx != 0.f) ? pcx : 0.f;
            float acy = (tcy != 0.f) ? pcy : 0.f;
            float acz = (tcz != 0.f) ? pcz : 0.f;
            float pdx = apx - acx, pdy = apy - acy, pdz = apz - acz;
            float tdx = tpx - tcx, tdy = tpy - tcy, tdz = tpz - tcz;
            float pd2 = pdx * pdx + pdy * pdy + pdz * pdz;
            float td2 = tdx * tdx + tdy * tdy + tdz * tdz;
            float pinv = (pd2 > 0.f) ? fast_rsq(pd2) : 0.f;
            float tinv = (td2 > 0.f) ? fast_rsq(td2) : 0.f;
            float dx = pdx * pinv - tdx * tinv;
            float dy = pdy * pinv - tdy * tinv;
            float dz = pdz * pinv - tdz * tinv;
            float m0 = (Bt[aM]      != 0.f) ? 1.f : 0.f;
            float m1 = (Bt[aM + 47] != 0.f) ? 1.f : 0.f;
            float m2 = (Bt[aM + 94] != 0.f) ? 1.f : 0.f;
            vel += m0 * dx * dx + m1 * dy * dy + m2 * dz * dz;
        }
    }
}

__global__ __launch_bounds__(BLOCK, 4) void reg_loss_main(
        const float* __restrict__ preds, const float* __restrict__ targets,
        float* __restrict__ wsL, float* __restrict__ wsV) {
    __shared__ float S[4][BUF_DW];         // 4 waves x 4832B = 19.3 KB/block
    __shared__ float redL[4], redV[4];

    const int t = threadIdx.x;
    const int lane = t & 63;
    const int wave = t >> 6;
    float* B = &S[wave][0];

    const long long wb =
        (long long)(blockIdx.x * 4 + wave) * (CHUNKS * CHUNK_DW);
    const float* gp = preds + wb;
    const float* gt = targets + wb;

    const int l4 = lane * 4;
    const bool tail = lane < 23;           // 23*16B = 368B tail (604-512 dw)
    const int off2 = tail ? (512 + l4) : l4;   // clamped: lanes >=23 re-read
                                               // lane-local bytes, masked at use

    // per-lane edge-task addresses (fixed across chunks): 9 VGPRs
    EdgeAddr ea;
#pragma unroll
    for (int k = 0; k < 3; ++k) {
        int task = lane + k * 64;
        bool a = task < CHUNK_TASKS;
        int r = a ? task / N_EDGES : 0;
        int e = a ? task - r * N_EDGES : 0;
        int roff = r * ROW;
        unsigned pk = c_edge[e];
        ea.aP[k] = roff + (int)(pk & 0xffff);
        ea.aC[k] = roff + (int)(pk >> 16);
        ea.aM[k] = roff + e;
    }

    float l1 = 0.f, vel = 0.f;
    float4 p0, p1, p2, t0, t1, t2;

    // prologue: issue chunk-0 loads (pinned; in flight while we fall into loop)
    p0 = ldg4_pin(gp + l4);       p1 = ldg4_pin(gp + 256 + l4);
    t0 = ldg4_pin(gt + l4);       t1 = ldg4_pin(gt + 256 + l4);
    p2 = ldg4_pin(gp + off2);     t2 = ldg4_pin(gt + off2);

#pragma unroll
    for (int c = 0; c < CHUNKS; ++c) {
        // chunk c's 6 loads are the only vmem in flight -> drain them.
        wait_vm<0>();
        __builtin_amdgcn_sched_barrier(0);   // rule #18: no consumer hoists
                                             // above the waitcnt

        // stage chunk c to LDS
        st4(B + l4,                  p0);
        st4(B + 256 + l4,            p1);
        st4(B + CHUNK_DW + l4,       t0);
        st4(B + CHUNK_DW + 256 + l4, t1);
        if (tail) {
            st4(B + 512 + l4,            p2);
            st4(B + CHUNK_DW + 512 + l4, t2);
        }

        // l1 term directly from the staging registers (no LDS read)
        acc_l1(p0, t0, l1);
        acc_l1(p1, t1, l1);
        if (tail) acc_l1(p2, t2, l1);

        // issue chunk c+1 loads: volatile asm w/ memory clobber -- cannot
        // sink past the edge-phase ds_reads, cannot hoist above the st4s.
        if (c + 1 < CHUNKS) {
            const float* cp = gp + (c + 1) * CHUNK_DW;
            const float* ct = gt + (c + 1) * CHUNK_DW;
            p0 = ldg4_pin(cp + l4);       p1 = ldg4_pin(cp + 256 + l4);
            t0 = ldg4_pin(ct + l4);       t1 = ldg4_pin(ct + 256 + l4);
            p2 = ldg4_pin(cp + off2);     t2 = ldg4_pin(ct + off2);
        }

        // edge gather from LDS; ~600cy that now covers the loads' latency.
        compute_edges(B, ea, lane, vel);
    }

    // ---- block reduction -> per-block partials ----
#pragma unroll
    for (int off = 32; off > 0; off >>= 1) {
        l1  += __shfl_down(l1, off);
        vel += __shfl_down(vel, off);
    }
    if (lane == 0) { redL[wave] = l1; redV[wave] = vel; }
    __syncthreads();
    if (t == 0) {
        wsL[blockIdx.x] = redL[0] + redL[1] + redL[2] + redL[3];
        wsV[blockIdx.x] = redV[0] + redV[1] + redV[2] + redV[3];
    }
}

__global__ __launch_bounds__(BLOCK) void reg_loss_finalize(
        const float* __restrict__ wsL, const float* __restrict__ wsV,
        float* __restrict__ out) {
    __shared__ double rl[4], rv[4];
    const int t = threadIdx.x;
    const int lane = t & 63;
    const int wave = t >> 6;
    double L = 0.0, V = 0.0;
    for (int k = t; k < GRID; k += BLOCK) { L += wsL[k]; V += wsV[k]; }
#pragma unroll
    for (int off = 32; off > 0; off >>= 1) {
        L += __shfl_down(L, off);
        V += __shfl_down(V, off);
    }
    if (lane == 0) { rl[wave] = L; rv[wave] = V; }
    __syncthreads();
    if (t == 0) {
        double Ls = rl[0] + rl[1] + rl[2] + rl[3];
        double Vs = rv[0] + rv[1] + rv[2] + rv[3];
        out[0] = (float)(Ls / ((double)N_ROWS * 151.0)
                       + 0.1 * (Vs / ((double)N_ROWS * 141.0)));
    }
}

extern "C" void kernel_launch(void* const* d_in, const int* in_sizes, int n_in,
                              void* d_out, int out_size, void* d_ws, size_t ws_size,
                              hipStream_t stream) {
    const float* preds   = (const float*)d_in[0];
    const float* targets = (const float*)d_in[1];
    float* wsL = (float*)d_ws;
    float* wsV = wsL + GRID;
    float* out = (float*)d_out;

    reg_loss_main<<<GRID, BLOCK, 0, stream>>>(preds, targets, wsL, wsV);
    reg_loss_finalize<<<1, BLOCK, 0, stream>>>(wsL, wsV, out);
}